// Round 23
// baseline (106.604 us; speedup 1.0000x reference)
//
#include <hip/hip_runtime.h>
#include <hip/hip_bf16.h>

// Block-sparse attention: B=2, S=4096, H=16, D=128, BS=64, LOCAL=8, GLOBAL=1.
// fp32 in/out, bf16 MFMA, flash softmax in exp2 domain (static max).
// Round 23 (base r22 = 92.3us): producer-consumer wave specialization.
// 384-thread blocks: waves 0-3 = consumers (16 q-rows each, NO staging code
// -> ~64 fewer regs -> 3 waves/SIMD fit), waves 4-5 = producers (global->
// cvt_pk->LDS into K/V double buffer). ONE lgkm barrier per kv-tile; staging
// latency fully off the consumer critical path (m114 wave-level overlap).
// Race audit: consumer reads buf[t&1] in window t, producer writes
// buf[(t+1)&1] in window t; all write<->read pairs barrier-separated.

typedef __bf16 bf16_t;
typedef bf16_t bf16x8 __attribute__((ext_vector_type(8)));
typedef float f32x4 __attribute__((ext_vector_type(4)));
typedef uint32_t u32x4 __attribute__((ext_vector_type(4)));

#define BSZ 64
#define DIM 128
#define NH 16
#define SEQ 4096
#define ROWSTRIDE (NH * DIM)

#define LGKM_BARRIER()                                          \
    do {                                                        \
        asm volatile("s_waitcnt lgkmcnt(0)" ::: "memory");      \
        __builtin_amdgcn_s_barrier();                           \
    } while (0)

__device__ __forceinline__ uint32_t cvt_pk_bf16(float lo, float hi) {
    uint32_t r;
    asm("v_cvt_pk_bf16_f32 %0, %1, %2" : "=v"(r) : "v"(lo), "v"(hi));
    return r;
}

// Kb: [64][128] bf16 per buffer, A = row*256 + col*2. Rank-5 swizzle (r22).
__device__ __forceinline__ uint32_t kb_swz(uint32_t A) {
    return A ^ (((A >> 8) & 7u) << 4) ^ (((A >> 11) & 1u) << 7);
}
// Vt: [128][64] bf16 per buffer, A = d*128 + k*2. Rank-5 swizzle (r22).
__device__ __forceinline__ uint32_t vt_swz(uint32_t A) {
    return A ^ (((A >> 9) & 7u) << 4) ^ (((A >> 9) & 1u) << 6) ^ (((A >> 12) & 3u) << 7);
}

__global__ __launch_bounds__(384) void sparse_attn_kernel(
    const float* __restrict__ q, const float* __restrict__ k,
    const float* __restrict__ v, float* __restrict__ out)
{
    __shared__ __align__(16) bf16_t Kb[2 * BSZ * DIM];   // 32768 B
    __shared__ __align__(16) bf16_t Vt[2 * DIM * BSZ];   // 32768 B (total 65536)

    // XCD-aware swizzle: 2048 wgs, 8 XCDs -> contiguous 256-chunk per XCD.
    const int L  = ((blockIdx.x & 7) << 8) | (blockIdx.x >> 3);
    const int qi = L & 63;
    const int h  = (L >> 6) & 15;
    const int b  = L >> 10;

    const int tid = threadIdx.x;

    const size_t bh_off = ((size_t)b * SEQ * NH + (size_t)h) * DIM;
    const float* kbh = k + bh_off;
    const float* vbh = v + bh_off;
    const int nnz = (qi < 8) ? (qi + 1) : 9;

    if (tid >= 256) {
        // ================= PRODUCER (waves 4-5) =================
        const int pl   = tid - 256;      // 0..127
        const int krow = pl >> 4;        // K: base row 0..7 (row = krow + 8i)
        const int kch8 = pl & 15;        // K: 8-float chunk
        const int vrb  = pl >> 5;        // V: row-group base 0..3 (vrg = vrb+4g)
        const int sc4p = pl & 31;        // V: float4 column

        #define PROD_STAGE(jb, bufOff)                                            \
        {                                                                         \
            const float* kb_ = kbh + (size_t)(jb) * 64 * ROWSTRIDE;               \
            const float* vb_ = vbh + (size_t)(jb) * 64 * ROWSTRIDE;               \
            float4 st[16];                                                        \
            _Pragma("unroll")                                                     \
            for (int i = 0; i < 8; ++i) {                                         \
                const float* p_ = kb_ + (size_t)(krow + 8 * i) * ROWSTRIDE        \
                                  + 8 * kch8;                                     \
                st[2 * i]     = *(const float4*)p_;                               \
                st[2 * i + 1] = *(const float4*)(p_ + 4);                         \
            }                                                                     \
            _Pragma("unroll")                                                     \
            for (int i = 0; i < 8; ++i) {                                         \
                const float4 a0 = st[2 * i], a1 = st[2 * i + 1];                  \
                u32x4 w = {cvt_pk_bf16(a0.x, a0.y), cvt_pk_bf16(a0.z, a0.w),      \
                           cvt_pk_bf16(a1.x, a1.y), cvt_pk_bf16(a1.z, a1.w)};     \
                const uint32_t A = kb_swz((uint32_t)((krow + 8 * i) * 256         \
                                                     + 16 * kch8));               \
                *(u32x4*)((char*)Kb + (bufOff) + A) = w;                          \
            }                                                                     \
            _Pragma("unroll")                                                     \
            for (int g = 0; g < 2; ++g) {                                         \
                const int vrg = vrb + 4 * g;                                      \
                const float* q_ = vb_ + (size_t)(8 * vrg) * ROWSTRIDE + 4 * sc4p; \
                _Pragma("unroll")                                                 \
                for (int i = 0; i < 8; ++i)                                       \
                    st[8 * g + i] = *(const float4*)(q_ + (size_t)i * ROWSTRIDE); \
            }                                                                     \
            _Pragma("unroll")                                                     \
            for (int g = 0; g < 2; ++g) {                                         \
                const int vrg = vrb + 4 * g;                                      \
                _Pragma("unroll")                                                 \
                for (int j2 = 0; j2 < 4; ++j2) {                                  \
                    u32x4 w = {cvt_pk_bf16(((const float*)&st[8*g+0])[j2],        \
                                           ((const float*)&st[8*g+1])[j2]),       \
                               cvt_pk_bf16(((const float*)&st[8*g+2])[j2],        \
                                           ((const float*)&st[8*g+3])[j2]),       \
                               cvt_pk_bf16(((const float*)&st[8*g+4])[j2],        \
                                           ((const float*)&st[8*g+5])[j2]),       \
                               cvt_pk_bf16(((const float*)&st[8*g+6])[j2],        \
                                           ((const float*)&st[8*g+7])[j2])};      \
                    const int d = 4 * sc4p + j2;                                  \
                    const uint32_t A = vt_swz((uint32_t)(d * 128 + 16 * vrg));    \
                    *(u32x4*)((char*)Vt + (bufOff) + A) = w;                      \
                }                                                                 \
            }                                                                     \
        }

        PROD_STAGE(0, 0);          // tile 0 -> buf 0
        LGKM_BARRIER();            // prologue barrier
        for (int t = 0; t < nnz; ++t) {
            if (t + 1 < nnz) {
                const int jn = (qi < 8) ? (t + 1) : (qi - 8 + t + 1);
                PROD_STAGE(jn, (uint32_t)(((t + 1) & 1) * 16384));
            }
            LGKM_BARRIER();
        }
        return;
    }

    // ================= CONSUMER (waves 0-3) =================
    const int wave = tid >> 6;
    const int lane = tid & 63;
    const int lr = lane & 15;
    const int lk = lane >> 4;
    const int k0 = lk * 8;

    const float scale2 = 0.12751649736230476f;  // (1/sqrt(128)) * log2(e)

    // ---- Q fragments, pre-scaled (wave owns q rows [qi*64+wave*16, +16)) ----
    bf16x8 qf[4];
    {
        const float* qrow = q + bh_off + (size_t)(qi * 64 + wave * 16 + lr) * ROWSTRIDE;
        #pragma unroll
        for (int kk = 0; kk < 4; ++kk) {
            const float4 a0 = *(const float4*)(qrow + 32 * kk + k0);
            const float4 a1 = *(const float4*)(qrow + 32 * kk + k0 + 4);
            u32x4 w = {cvt_pk_bf16(a0.x * scale2, a0.y * scale2),
                       cvt_pk_bf16(a0.z * scale2, a0.w * scale2),
                       cvt_pk_bf16(a1.x * scale2, a1.y * scale2),
                       cvt_pk_bf16(a1.z * scale2, a1.w * scale2)};
            qf[kk] = *(bf16x8*)&w;
        }
    }

    f32x4 oacc[8];
    #pragma unroll
    for (int n = 0; n < 8; ++n) oacc[n] = (f32x4){0.f, 0.f, 0.f, 0.f};
    float lrun = 0.f;

    const int qrow_local = wave * 16 + lr;

    // ---- push-exchange addressing (constant per lane) ----
    const int bit0 = lk & 1;
    const int bit1 = lk >> 1;
    const bool hi  = (lk & 2) != 0;
    const int Dlo  = (lr + 16 * bit1) << 2;
    const int Dhi  = Dlo + (32 << 2);
    const int addrA = bit0 ? Dhi : Dlo;
    const int addrB = bit0 ? Dlo : Dhi;

    LGKM_BARRIER();   // prologue barrier (tile 0 staged by producers)

    for (int t = 0; t < nnz; ++t) {
        const int j = (qi < 8) ? t : ((t == 0) ? 0 : (qi - 8 + t));
        const uint32_t bufOff = (uint32_t)((t & 1) * 16384);

        // ---- S^T = K*Q^T from Kb[buf] ----
        f32x4 sacc[4];
        #pragma unroll
        for (int n = 0; n < 4; ++n) {
            f32x4 a = (f32x4){0.f, 0.f, 0.f, 0.f};
            #pragma unroll
            for (int kk = 0; kk < 4; ++kk) {
                const uint32_t A = kb_swz((uint32_t)((16 * n + lr) * 256 + 64 * kk + 16 * lk));
                bf16x8 kf = *(const bf16x8*)((const char*)Kb + bufOff + A);
                a = __builtin_amdgcn_mfma_f32_16x16x32_bf16(kf, qf[kk], a, 0, 0, 0);
            }
            sacc[n] = a;
        }

        // ---- mask (diag only) ----
        if (j == qi) {
            #pragma unroll
            for (int n = 0; n < 4; ++n)
                #pragma unroll
                for (int r = 0; r < 4; ++r) {
                    if (16 * n + 4 * lk + r > qrow_local) sacc[n][r] = -1.0e30f;
                }
        }

        // ---- static-max softmax: p = 2^s; cvt_pk output IS the chunk word ----
        uint32_t ch[8];
        #pragma unroll
        for (int n = 0; n < 4; ++n) {
            float p0 = exp2f(sacc[n][0]);
            float p1 = exp2f(sacc[n][1]);
            float p2 = exp2f(sacc[n][2]);
            float p3 = exp2f(sacc[n][3]);
            lrun += (p0 + p1) + (p2 + p3);
            ch[2 * n]     = cvt_pk_bf16(p0, p1);
            ch[2 * n + 1] = cvt_pk_bf16(p2, p3);
        }

        // ---- push-model exchange: paf[kk] = P[q=lr][k=32kk+8lk..+7] ----
        bf16x8 paf[2];
        #pragma unroll
        for (int kk = 0; kk < 2; ++kk) {
            uint32_t r0 = (uint32_t)__builtin_amdgcn_ds_permute(
                addrA, (int)(bit0 ? ch[4 * kk + 2] : ch[4 * kk + 0]));
            uint32_t r1 = (uint32_t)__builtin_amdgcn_ds_permute(
                addrA, (int)(bit0 ? ch[4 * kk + 3] : ch[4 * kk + 1]));
            uint32_t r2 = (uint32_t)__builtin_amdgcn_ds_permute(
                addrB, (int)(bit0 ? ch[4 * kk + 0] : ch[4 * kk + 2]));
            uint32_t r3 = (uint32_t)__builtin_amdgcn_ds_permute(
                addrB, (int)(bit0 ? ch[4 * kk + 1] : ch[4 * kk + 3]));
            u32x4 tv = {hi ? r2 : r0, hi ? r3 : r1,
                        hi ? r0 : r2, hi ? r1 : r3};
            paf[kk] = *(bf16x8*)&tv;
        }

        // ---- O += P * V from Vt[buf] ----
        #pragma unroll
        for (int n = 0; n < 8; ++n) {
            f32x4 a = oacc[n];
            #pragma unroll
            for (int kk = 0; kk < 2; ++kk) {
                const uint32_t Av = vt_swz((uint32_t)((16 * n + lr) * 128 + 64 * kk + 16 * lk));
                bf16x8 vf = *(const bf16x8*)((const char*)Vt + bufOff + Av);
                a = __builtin_amdgcn_mfma_f32_16x16x32_bf16(paf[kk], vf, a, 0, 0, 0);
            }
            oacc[n] = a;
        }

        LGKM_BARRIER();
    }

    // ---- epilogue: total l per q-row, redistribute to oacc rows, store ----
    float lrtot = lrun;
    lrtot += __shfl_xor(lrtot, 16);
    lrtot += __shfl_xor(lrtot, 32);
    float* obase = out + bh_off + (size_t)(qi * 64 + wave * 16) * ROWSTRIDE;
    #pragma unroll
    for (int r = 0; r < 4; ++r) {
        const float inv = 1.0f / __shfl(lrtot, 4 * lk + r);
        float* orow = obase + (size_t)(4 * lk + r) * ROWSTRIDE;
        #pragma unroll
        for (int n = 0; n < 8; ++n) {
            orow[16 * n + lr] = oacc[n][r] * inv;
        }
    }
}

extern "C" void kernel_launch(void* const* d_in, const int* in_sizes, int n_in,
                              void* d_out, int out_size, void* d_ws, size_t ws_size,
                              hipStream_t stream) {
    const float* q = (const float*)d_in[0];
    const float* k = (const float*)d_in[1];
    const float* v = (const float*)d_in[2];
    float* out = (float*)d_out;
    sparse_attn_kernel<<<dim3(2048), dim3(384), 0, stream>>>(q, k, v, out);
}

// Round 24
// 96.047 us; speedup vs baseline: 1.1099x; 1.1099x over previous
//
#include <hip/hip_runtime.h>
#include <hip/hip_bf16.h>

// Block-sparse attention: B=2, S=4096, H=16, D=128, BS=64, LOCAL=8, GLOBAL=1.
// fp32 in/out, bf16 MFMA, flash softmax in exp2 domain (static max).
// Round 24 (base r22 = 92.3us): barrier halving. Tiles processed in PAIRS with
// alternating LDS buffers A/B: STAGE_A -> bar -> COMPUTE(t,A) -> STAGE_B ->
// bar -> COMPUTE(t+1,B). One barrier per kv-block (was 2); each compute half
// covers the other half's global loads. Race-audited (see schedule comments).
// LDS 64KB -> still 2 blocks/CU (= register limit). Body identical to r22.

typedef __bf16 bf16_t;
typedef bf16_t bf16x8 __attribute__((ext_vector_type(8)));
typedef float f32x4 __attribute__((ext_vector_type(4)));
typedef uint32_t u32x4 __attribute__((ext_vector_type(4)));

#define BSZ 64
#define DIM 128
#define NH 16
#define SEQ 4096
#define ROWSTRIDE (NH * DIM)

#define LGKM_BARRIER()                                          \
    do {                                                        \
        asm volatile("s_waitcnt lgkmcnt(0)" ::: "memory");      \
        __builtin_amdgcn_s_barrier();                           \
    } while (0)

__device__ __forceinline__ uint32_t cvt_pk_bf16(float lo, float hi) {
    uint32_t r;
    asm("v_cvt_pk_bf16_f32 %0, %1, %2" : "=v"(r) : "v"(lo), "v"(hi));
    return r;
}

// Kb: [64][128] bf16 per buffer, A = row*256 + col*2. Rank-5 swizzle (r22).
__device__ __forceinline__ uint32_t kb_swz(uint32_t A) {
    return A ^ (((A >> 8) & 7u) << 4) ^ (((A >> 11) & 1u) << 7);
}
// Vt: [128][64] bf16 per buffer, A = d*128 + k*2. Rank-5 swizzle (r22).
__device__ __forceinline__ uint32_t vt_swz(uint32_t A) {
    return A ^ (((A >> 9) & 7u) << 4) ^ (((A >> 9) & 1u) << 6) ^ (((A >> 12) & 3u) << 7);
}

__global__ __launch_bounds__(256) void sparse_attn_kernel(
    const float* __restrict__ q, const float* __restrict__ k,
    const float* __restrict__ v, float* __restrict__ out)
{
    __shared__ __align__(16) bf16_t Kb[2 * BSZ * DIM];   // 32768 B
    __shared__ __align__(16) bf16_t Vt[2 * DIM * BSZ];   // 32768 B (total 65536)

    // XCD-aware swizzle: 2048 wgs, 8 XCDs -> contiguous 256-chunk per XCD.
    const int L  = ((blockIdx.x & 7) << 8) | (blockIdx.x >> 3);
    const int qi = L & 63;
    const int h  = (L >> 6) & 15;
    const int b  = L >> 10;

    const int tid  = threadIdx.x;
    const int wave = tid >> 6;
    const int lane = tid & 63;
    const int lr = lane & 15;
    const int lk = lane >> 4;
    const int k0 = lk * 8;

    const int krr = tid >> 4;   // K staging: row-in-group 0..15
    const int kc8 = tid & 15;   // K staging: 8-float chunk 0..15
    const int vr  = tid >> 5;   // V staging: 8-row group 0..7
    const int sc4 = tid & 31;   // V staging: float4 column 0..31

    const float scale2 = 0.12751649736230476f;  // (1/sqrt(128)) * log2(e)

    const size_t bh_off = ((size_t)b * SEQ * NH + (size_t)h) * DIM;
    const float* kbh = k + bh_off;
    const float* vbh = v + bh_off;

    // ---- Q fragments, pre-scaled (wave owns q rows [qi*64+wave*16, +16)) ----
    bf16x8 qf[4];
    {
        const float* qrow = q + bh_off + (size_t)(qi * 64 + wave * 16 + lr) * ROWSTRIDE;
        #pragma unroll
        for (int kk = 0; kk < 4; ++kk) {
            const float4 a0 = *(const float4*)(qrow + 32 * kk + k0);
            const float4 a1 = *(const float4*)(qrow + 32 * kk + k0 + 4);
            u32x4 w = {cvt_pk_bf16(a0.x * scale2, a0.y * scale2),
                       cvt_pk_bf16(a0.z * scale2, a0.w * scale2),
                       cvt_pk_bf16(a1.x * scale2, a1.y * scale2),
                       cvt_pk_bf16(a1.z * scale2, a1.w * scale2)};
            qf[kk] = *(bf16x8*)&w;
        }
    }

    f32x4 oacc[8];
    #pragma unroll
    for (int n = 0; n < 8; ++n) oacc[n] = (f32x4){0.f, 0.f, 0.f, 0.f};
    float lrun = 0.f;   // per-lane partial row-sum; this lane's q-row is lr

    const int qrow_local = wave * 16 + lr;
    const int nnz = (qi < 8) ? (qi + 1) : 9;

    // ---- push-exchange addressing (constant per lane) ----
    const int bit0 = lk & 1;
    const int bit1 = lk >> 1;
    const bool hi  = (lk & 2) != 0;
    const int Dlo  = (lr + 16 * bit1) << 2;
    const int Dhi  = Dlo + (32 << 2);
    const int addrA = bit0 ? Dhi : Dlo;
    const int addrB = bit0 ? Dlo : Dhi;

    float4 kreg[8];
    float4 vreg[8];

    auto j_of = [&](int t) -> int {
        return (qi < 8) ? t : ((t == 0) ? 0 : (qi - 8 + t));
    };

    auto load_kv = [&](int jb) {
        #pragma unroll
        for (int i = 0; i < 4; ++i) {
            const float* p_ = kbh + (size_t)(jb * 64 + 16 * i + krr) * ROWSTRIDE + 8 * kc8;
            kreg[2 * i]     = *(const float4*)(p_);
            kreg[2 * i + 1] = *(const float4*)(p_ + 4);
        }
        const float* vb_ = vbh + (size_t)(jb * 64 + 8 * vr) * ROWSTRIDE + 4 * sc4;
        #pragma unroll
        for (int i = 0; i < 8; ++i)
            vreg[i] = *(const float4*)(vb_ + (size_t)i * ROWSTRIDE);
    };

    auto stage_write = [&](uint32_t off) {
        #pragma unroll
        for (int i = 0; i < 4; ++i) {
            const float4 a0 = kreg[2 * i];
            const float4 a1 = kreg[2 * i + 1];
            u32x4 w = {cvt_pk_bf16(a0.x, a0.y), cvt_pk_bf16(a0.z, a0.w),
                       cvt_pk_bf16(a1.x, a1.y), cvt_pk_bf16(a1.z, a1.w)};
            const uint32_t A = kb_swz((uint32_t)((16 * i + krr) * 256 + 16 * kc8));
            *(u32x4*)((char*)Kb + off + A) = w;
        }
        #pragma unroll
        for (int j2 = 0; j2 < 4; ++j2) {
            u32x4 w = {cvt_pk_bf16(((const float*)&vreg[0])[j2], ((const float*)&vreg[1])[j2]),
                       cvt_pk_bf16(((const float*)&vreg[2])[j2], ((const float*)&vreg[3])[j2]),
                       cvt_pk_bf16(((const float*)&vreg[4])[j2], ((const float*)&vreg[5])[j2]),
                       cvt_pk_bf16(((const float*)&vreg[6])[j2], ((const float*)&vreg[7])[j2])};
            const int d = 4 * sc4 + j2;
            const uint32_t A = vt_swz((uint32_t)(d * 128 + 16 * vr));
            *(u32x4*)((char*)Vt + off + A) = w;
        }
    };

    auto compute_tile = [&](int jj, uint32_t off) {
        // ---- S^T = K*Q^T ----
        f32x4 sacc[4];
        #pragma unroll
        for (int n = 0; n < 4; ++n) {
            f32x4 a = (f32x4){0.f, 0.f, 0.f, 0.f};
            #pragma unroll
            for (int kk = 0; kk < 4; ++kk) {
                const uint32_t A = kb_swz((uint32_t)((16 * n + lr) * 256 + 64 * kk + 16 * lk));
                bf16x8 kf = *(const bf16x8*)((const char*)Kb + off + A);
                a = __builtin_amdgcn_mfma_f32_16x16x32_bf16(kf, qf[kk], a, 0, 0, 0);
            }
            sacc[n] = a;
        }
        // ---- mask (diag only) ----
        if (jj == qi) {
            #pragma unroll
            for (int n = 0; n < 4; ++n)
                #pragma unroll
                for (int r = 0; r < 4; ++r) {
                    if (16 * n + 4 * lk + r > qrow_local) sacc[n][r] = -1.0e30f;
                }
        }
        // ---- static-max softmax ----
        uint32_t ch[8];
        #pragma unroll
        for (int n = 0; n < 4; ++n) {
            float p0 = exp2f(sacc[n][0]);
            float p1 = exp2f(sacc[n][1]);
            float p2 = exp2f(sacc[n][2]);
            float p3 = exp2f(sacc[n][3]);
            lrun += (p0 + p1) + (p2 + p3);
            ch[2 * n]     = cvt_pk_bf16(p0, p1);
            ch[2 * n + 1] = cvt_pk_bf16(p2, p3);
        }
        // ---- push-model exchange ----
        bf16x8 paf[2];
        #pragma unroll
        for (int kk = 0; kk < 2; ++kk) {
            uint32_t r0 = (uint32_t)__builtin_amdgcn_ds_permute(
                addrA, (int)(bit0 ? ch[4 * kk + 2] : ch[4 * kk + 0]));
            uint32_t r1 = (uint32_t)__builtin_amdgcn_ds_permute(
                addrA, (int)(bit0 ? ch[4 * kk + 3] : ch[4 * kk + 1]));
            uint32_t r2 = (uint32_t)__builtin_amdgcn_ds_permute(
                addrB, (int)(bit0 ? ch[4 * kk + 0] : ch[4 * kk + 2]));
            uint32_t r3 = (uint32_t)__builtin_amdgcn_ds_permute(
                addrB, (int)(bit0 ? ch[4 * kk + 1] : ch[4 * kk + 3]));
            u32x4 tv = {hi ? r2 : r0, hi ? r3 : r1,
                        hi ? r0 : r2, hi ? r1 : r3};
            paf[kk] = *(bf16x8*)&tv;
        }
        // ---- O += P * V ----
        #pragma unroll
        for (int n = 0; n < 8; ++n) {
            f32x4 a = oacc[n];
            #pragma unroll
            for (int kk = 0; kk < 2; ++kk) {
                const uint32_t Av = vt_swz((uint32_t)((16 * n + lr) * 128 + 64 * kk + 16 * lk));
                bf16x8 vf = *(const bf16x8*)((const char*)Vt + off + Av);
                a = __builtin_amdgcn_mfma_f32_16x16x32_bf16(paf[kk], vf, a, 0, 0, 0);
            }
            oacc[n] = a;
        }
    };

    load_kv(0);  // tile 0

    for (int t = 0; t < nnz; t += 2) {
        // regs hold tile t
        stage_write(0);                           // buf A
        if (t + 1 < nnz) { load_kv(j_of(t + 1)); }
        LGKM_BARRIER();                           // publish A (A-writes vs old A-reads sep. by prev bar)
        compute_tile(j_of(t), 0);                 // covers loads of t+1
        if (t + 1 < nnz) {
            stage_write(16384);                   // buf B (old B-reads sep. by barrier above)
            if (t + 2 < nnz) { load_kv(j_of(t + 2)); }
            LGKM_BARRIER();                       // publish B; A-reads done pre-barrier
            compute_tile(j_of(t + 1), 16384);     // covers loads of t+2
        }
    }

    // ---- epilogue: total l per q-row, redistribute to oacc rows, store ----
    float lrtot = lrun;
    lrtot += __shfl_xor(lrtot, 16);
    lrtot += __shfl_xor(lrtot, 32);
    float* obase = out + bh_off + (size_t)(qi * 64 + wave * 16) * ROWSTRIDE;
    #pragma unroll
    for (int r = 0; r < 4; ++r) {
        const float inv = 1.0f / __shfl(lrtot, 4 * lk + r);
        float* orow = obase + (size_t)(4 * lk + r) * ROWSTRIDE;
        #pragma unroll
        for (int n = 0; n < 8; ++n) {
            orow[16 * n + lr] = oacc[n][r] * inv;
        }
    }
}

extern "C" void kernel_launch(void* const* d_in, const int* in_sizes, int n_in,
                              void* d_out, int out_size, void* d_ws, size_t ws_size,
                              hipStream_t stream) {
    const float* q = (const float*)d_in[0];
    const float* k = (const float*)d_in[1];
    const float* v = (const float*)d_in[2];
    float* out = (float*)d_out;
    sparse_attn_kernel<<<dim3(2048), dim3(256), 0, stream>>>(q, k, v, out);
}